// Round 4
// baseline (229.130 us; speedup 1.0000x reference)
//
#include <hip/hip_runtime.h>

#define NN 64
// ---- ws layout (uint4 units) ----
#define B_PER_MAT (8 * 14 * 64) // 7168
#define B_OFF 0
#define AGL_PER_MAT (8 * 13 * 64) // 6656
#define AGL_OFF (128 * B_PER_MAT) // 917504
#define ALO_PER_MAT (8 * 7 * 64) // 3584
#define ALO_OFF (AGL_OFF + 128 * AGL_PER_MAT) // 1769472
#define PART_OFF_F ((ALO_OFF + 384 * ALO_PER_MAT) * 4) // float offset 12582912

typedef __attribute__((ext_vector_type(8))) short short8;
typedef __attribute__((ext_vector_type(4))) float f32x4;

__device__ __forceinline__ float waveSum(float v) {
#pragma unroll
  for (int m = 1; m < 64; m <<= 1) v += __shfl_xor(v, m, 64);
  return v;
}

// RNE float -> bf16
__device__ __forceinline__ unsigned short f2bf(float f) {
  unsigned u = __builtin_bit_cast(unsigned, f);
  u += 0x7FFFu + ((u >> 16) & 1u);
  return (unsigned short)(u >> 16);
}
__device__ __forceinline__ unsigned packbf(float a, float b) {
  return (unsigned)f2bf(a) | ((unsigned)f2bf(b) << 16);
}

// All three inputs -> bf16 MFMA fragments.
// frag layout per mat: [kc8(8)][tile][lane=quad*16+li][8 bf16]
// element e of frag = src[(kc8*32 + quad*8 + e)*ncols + tile*16 + li]
// One block per matrix; each task produces 4 frags for 4 consecutive cols.
__global__ void __launch_bounds__(256) convert_kernel(
    const float* __restrict__ gl_sa, const float* __restrict__ lo_sa,
    const float* __restrict__ gl_pr, uint4* __restrict__ ws) {
  int b = blockIdx.x;
  const float* src;
  uint4* dst;
  int ncols, nquads, ntiles;
  if (b < 128) {
    src = gl_pr + (size_t)b * 256 * 196;
    dst = ws + B_OFF + (size_t)b * B_PER_MAT;
    ncols = 196; nquads = 56; ntiles = 14;
  } else if (b < 256) {
    int m = b - 128;
    src = gl_sa + (size_t)m * 256 * 196;
    dst = ws + AGL_OFF + (size_t)m * AGL_PER_MAT;
    ncols = 196; nquads = 52; ntiles = 13;
  } else {
    int m = b - 256;
    src = lo_sa + (size_t)m * 256 * 100;
    dst = ws + ALO_OFF + (size_t)m * ALO_PER_MAT;
    ncols = 100; nquads = 28; ntiles = 7;
  }
  const int ntasks = nquads * 32;
  for (int task = threadIdx.x; task < ntasks; task += 256) {
    int oct = task / nquads;      // kc8*4 + quad
    int cq = task - oct * nquads; // col-quad
    int kc8 = oct >> 2, quad = oct & 3;
    int col0 = cq * 4;
    uint4 u[4];
    if (col0 < ncols) {
      const float* p = src + (size_t)(kc8 * 32 + quad * 8) * ncols + col0;
      float g[8][4];
#pragma unroll
      for (int e = 0; e < 8; ++e) {
        float4 v = *(const float4*)(p + e * ncols);
        g[e][0] = v.x; g[e][1] = v.y; g[e][2] = v.z; g[e][3] = v.w;
      }
#pragma unroll
      for (int j = 0; j < 4; ++j) {
        u[j].x = packbf(g[0][j], g[1][j]);
        u[j].y = packbf(g[2][j], g[3][j]);
        u[j].z = packbf(g[4][j], g[5][j]);
        u[j].w = packbf(g[6][j], g[7][j]);
      }
    } else { // pad cols (>= ncols): zero
      u[0] = u[1] = u[2] = u[3] = make_uint4(0, 0, 0, 0);
    }
    int tile = col0 >> 4, li0 = col0 & 15;
    uint4* d = dst + ((size_t)(kc8 * ntiles + tile) * 64 + quad * 16 + li0);
    d[0] = u[0]; d[1] = u[1]; d[2] = u[2]; d[3] = u[3];
  }
}

__global__ void __launch_bounds__(256, 3) triplet_main(
    const uint4* __restrict__ ws, const float* __restrict__ coords,
    float* __restrict__ partials) {
  __shared__ float red[3][4];
  const int tid = threadIdx.x;
  const int lane = tid & 63;
  const int li = lane & 15;
  const int quad = lane >> 4;
  const int w = tid >> 6;

  int b = blockIdx.x;
  const uint4 *abase, *bbase;
  const float *cqp, *ckp;
  int Q, Wq, ntA, rowbase;
  if (b < 512) {
    // gl terms: t=0 -> q=gl_sa[1],k=gl_pr[0]; t=1 -> q=gl_sa[0],k=gl_pr[1]
    int t = b >> 8, rem = b & 255;
    int n = rem >> 2, g = rem & 3;
    rowbase = g * 64;
    int qi = 1 - t, kj = t;
    Q = 196; Wq = 14; ntA = 13;
    abase = ws + AGL_OFF + (size_t)(qi * NN + n) * AGL_PER_MAT;
    bbase = ws + B_OFF + (size_t)(kj * NN + n) * B_PER_MAT;
    cqp = coords + (qi * NN + n) * 4;
    ckp = coords + (kj * NN + n) * 4;
  } else {
    int bb = b - 512;
    int t = bb / 128, rem = bb % 128;
    int n = rem >> 1, g = rem & 1;
    rowbase = g * 64;
    int j = t / 6, i = t % 6;
    Q = 100; Wq = 10; ntA = 7;
    abase = ws + ALO_OFF + (size_t)(i * NN + n) * ALO_PER_MAT;
    bbase = ws + B_OFF + (size_t)(j * NN + n) * B_PER_MAT;
    cqp = coords + ((2 + i) * NN + n) * 4;
    ckp = coords + (j * NN + n) * 4;
  }
  const int rt = (rowbase >> 4) + w; // this wave's A row-tile

  f32x4 acc[14];
#pragma unroll
  for (int t = 0; t < 14; ++t) acc[t] = 0.0f;

  if (rt < ntA) { // wave-uniform; idle waves skip straight to epilogue guards
    const uint4* ap = abase + (size_t)rt * 64 + lane;
    const uint4* bp = bbase + lane;
#pragma unroll 1
    for (int kc8 = 0; kc8 < 8; ++kc8) {
      short8 af = __builtin_bit_cast(short8, ap[(size_t)kc8 * ntA * 64]);
#pragma unroll
      for (int t = 0; t < 14; ++t) {
        short8 bf = __builtin_bit_cast(short8, bp[((size_t)kc8 * 14 + t) * 64]);
        acc[t] = __builtin_amdgcn_mfma_f32_16x16x32_bf16(af, bf, acc[t], 0, 0, 0);
      }
    }
  }

  // ---- geometry ----
  const float qx0 = cqp[0], qy0 = cqp[1];
  const float bwq = (cqp[2] - qx0) / (float)Wq;
  const float bhq = (cqp[3] - qy0) / (float)Wq;
  const float kx0 = ckp[0], ky0 = ckp[1];
  const float bwk = (ckp[2] - kx0) / 14.0f;
  const float bhk = (ckp[3] - ky0) / 14.0f;
  const float qd = sqrtf(bwq * bwq + bhq * bhq);
  const float kd = sqrtf(bwk * bwk + bhk * bhk);
  const float md = fmaxf(qd, kd);
  const float INFV = __builtin_inff();

  float ckx[14], cky[14];
  unsigned kvalid = 0;
#pragma unroll
  for (int t = 0; t < 14; ++t) {
    int col = t * 16 + li;
    if (col < 196) kvalid |= (1u << t);
    int xk = col % 14, yk = col / 14;
    ckx[t] = ((float)xk + 0.5f) * bwk + kx0;
    cky[t] = ((float)yk + 0.5f) * bhk + ky0;
  }

  // ---- fused epilogue on MFMA C layout: quad owns rows quad*4+reg ----
  float psum = 0.f, pcnt = 0.f, nsum = 0.f;
#pragma unroll
  for (int rg = 0; rg < 4; ++rg) {
    int r = rowbase + w * 16 + quad * 4 + rg; // quad-uniform
    if (r < Q) {
      int x = r % Wq, y = r / Wq;
      float cqx = ((float)x + 0.5f) * bwq + qx0;
      float cqy = ((float)y + 0.5f) * bhq + qy0;
      float mv[14];
#pragma unroll
      for (int t = 0; t < 14; ++t) {
        float v = -2.0f * acc[t][rg];
        float dx = cqx - ckx[t], dy = cqy - cky[t];
        float dist = sqrtf(dx * dx + dy * dy) / md;
        bool kv = (kvalid >> t) & 1;
        bool pos = kv && (dist < 0.7f);
        psum += pos ? v : 0.0f;
        pcnt += pos ? 1.0f : 0.0f;
        mv[t] = (kv && !pos) ? v : INFV;
      }
      float total = 0.f, first = 0.f;
#pragma unroll 1
      for (int s = 0; s < 10; ++s) {
        float lm = mv[0];
#pragma unroll
        for (int t = 1; t < 14; ++t) lm = fminf(lm, mv[t]);
        float m = lm;
        m = fminf(m, __shfl_xor(m, 1));
        m = fminf(m, __shfl_xor(m, 2));
        m = fminf(m, __shfl_xor(m, 4));
        m = fminf(m, __shfl_xor(m, 8));
        if (s == 0) first = m;
        total += m;
        unsigned long long bal = __ballot(lm == m);
        unsigned qb = (unsigned)((bal >> (quad * 16)) & 0xFFFFull);
        int leader = __ffs(qb) - 1;
        if (li == leader) {
          bool done = false;
#pragma unroll
          for (int t = 0; t < 14; ++t) {
            bool hit = !done && (mv[t] == m);
            mv[t] = hit ? INFV : mv[t];
            done = done || hit;
          }
        }
      }
      if (li == 0) nsum += (total - first) * (1.0f / 9.0f);
    }
  }

  psum = waveSum(psum);
  pcnt = waveSum(pcnt);
  nsum = waveSum(nsum);
  if (lane == 0) {
    red[0][w] = psum;
    red[1][w] = pcnt;
    red[2][w] = nsum;
  }
  __syncthreads();
  if (tid == 0) {
    float* pb = partials + (size_t)blockIdx.x * 3;
    pb[0] = red[0][0] + red[0][1] + red[0][2] + red[0][3];
    pb[1] = red[1][0] + red[1][1] + red[1][2] + red[1][3];
    pb[2] = red[2][0] + red[2][1] + red[2][2] + red[2][3];
  }
}

__global__ void __launch_bounds__(256) finalize_kernel(
    const float* __restrict__ partials, float* __restrict__ out) {
  int tid = threadIdx.x;
  float sum = 0.f;
  for (int e = tid; e < 14 * NN; e += 256) {
    float P = 0.f, C = 0.f, Ns = 0.f, Qf;
    if (e < 128) {
      int t = e >> 6, n = e & 63;
      Qf = 196.0f;
      int base = (t * 256 + n * 4) * 3;
#pragma unroll
      for (int g = 0; g < 4; ++g) {
        P += partials[base + 3 * g];
        C += partials[base + 3 * g + 1];
        Ns += partials[base + 3 * g + 2];
      }
    } else {
      int s = e - 128;
      int t = s >> 6, n = s & 63;
      Qf = 100.0f;
      int base = (512 + t * 128 + n * 2) * 3;
#pragma unroll
      for (int g = 0; g < 2; ++g) {
        P += partials[base + 3 * g];
        C += partials[base + 3 * g + 1];
        Ns += partials[base + 3 * g + 2];
      }
    }
    float positives = P / (C + 1e-6f);
    float negatives = Ns / Qf;
    sum += fmaxf(0.0f, 100.0f - (negatives - 2.0f * positives));
  }
  sum = waveSum(sum);
  __shared__ float ssum[4];
  if ((tid & 63) == 0) ssum[tid >> 6] = sum;
  __syncthreads();
  if (tid == 0) out[0] = (ssum[0] + ssum[1] + ssum[2] + ssum[3]) * (1.0f / (14 * NN));
}

extern "C" void kernel_launch(void* const* d_in, const int* in_sizes, int n_in,
                              void* d_out, int out_size, void* d_ws, size_t ws_size,
                              hipStream_t stream) {
  const float* gl_sa = (const float*)d_in[0];
  const float* lo_sa = (const float*)d_in[1];
  const float* gl_pr = (const float*)d_in[2];
  const float* coords = (const float*)d_in[3];
  uint4* frags = (uint4*)d_ws;
  float* partials = (float*)d_ws + PART_OFF_F;
  float* out = (float*)d_out;

  convert_kernel<<<640, 256, 0, stream>>>(gl_sa, lo_sa, gl_pr, frags);
  triplet_main<<<2048, 256, 0, stream>>>(frags, coords, partials);
  finalize_kernel<<<1, 256, 0, stream>>>(partials, out);
}

// Round 5
// 209.926 us; speedup vs baseline: 1.0915x; 1.0915x over previous
//
#include <hip/hip_runtime.h>

#define NN 64
// ---- ws layout (uint4 units) ----
#define B_PER_MAT (8 * 14 * 64) // 7168
#define B_OFF 0
#define AGL_PER_MAT (8 * 13 * 64) // 6656
#define AGL_OFF (128 * B_PER_MAT) // 917504
#define ALO_PER_MAT (8 * 7 * 64) // 3584
#define ALO_OFF (AGL_OFF + 128 * AGL_PER_MAT) // 1769472
#define PART_OFF_F ((ALO_OFF + 384 * ALO_PER_MAT) * 4) // float offset 12582912

#define LROWS 236 // LDS row stride in ushorts (472 B: 8B-aligned, 2-way max alias)

typedef __attribute__((ext_vector_type(8))) short short8;
typedef __attribute__((ext_vector_type(4))) float f32x4;

__device__ __forceinline__ float waveSum(float v) {
#pragma unroll
  for (int m = 1; m < 64; m <<= 1) v += __shfl_xor(v, m, 64);
  return v;
}

// min across each 16-lane DPP row via quad_perm/row_ror (VALU, no LDS)
__device__ __forceinline__ float rowMin16(float v) {
  int x = __builtin_bit_cast(int, v);
  v = fminf(v, __builtin_bit_cast(float, __builtin_amdgcn_update_dpp(x, x, 0xB1, 0xF, 0xF, true)));
  x = __builtin_bit_cast(int, v);
  v = fminf(v, __builtin_bit_cast(float, __builtin_amdgcn_update_dpp(x, x, 0x4E, 0xF, 0xF, true)));
  x = __builtin_bit_cast(int, v);
  v = fminf(v, __builtin_bit_cast(float, __builtin_amdgcn_update_dpp(x, x, 0x124, 0xF, 0xF, true)));
  x = __builtin_bit_cast(int, v);
  v = fminf(v, __builtin_bit_cast(float, __builtin_amdgcn_update_dpp(x, x, 0x128, 0xF, 0xF, true)));
  return v;
}

// RNE float -> bf16
__device__ __forceinline__ unsigned short f2bf(float f) {
  unsigned u = __builtin_bit_cast(unsigned, f);
  u += 0x7FFFu + ((u >> 16) & 1u);
  return (unsigned short)(u >> 16);
}

// One block per (matrix, 32-channel slice): coalesced fp32 read -> bf16 LDS
// transpose -> MFMA fragment layout in ws.
// frag layout per mat: [kc8(8)][tile][lane=quad*16+li][8 bf16]
// element e of frag = src[(kc8*32 + quad*8 + e)*ncols + tile*16 + li]
__global__ void __launch_bounds__(256) convert_kernel(
    const float* __restrict__ gl_sa, const float* __restrict__ lo_sa,
    const float* __restrict__ gl_pr, uint4* __restrict__ ws) {
  __shared__ unsigned short lds[32][LROWS];
  const int b = blockIdx.x;
  const int m = b >> 3, kc8 = b & 7;
  const int tid = threadIdx.x;
  const float* src;
  uint4* dst;
  int ncols, ntiles;
  if (m < 128) {
    src = gl_pr + (size_t)m * 256 * 196;
    dst = ws + B_OFF + (size_t)m * B_PER_MAT + kc8 * 14 * 64;
    ncols = 196; ntiles = 14;
  } else if (m < 256) {
    int mm = m - 128;
    src = gl_sa + (size_t)mm * 256 * 196;
    dst = ws + AGL_OFF + (size_t)mm * AGL_PER_MAT + kc8 * 13 * 64;
    ncols = 196; ntiles = 13;
  } else {
    int mm = m - 256;
    src = lo_sa + (size_t)mm * 256 * 100;
    dst = ws + ALO_OFF + (size_t)mm * ALO_PER_MAT + kc8 * 7 * 64;
    ncols = 100; ntiles = 7;
  }
  src += (size_t)kc8 * 32 * ncols;

  // stage 1: coalesced float4 loads -> bf16 -> LDS rows
  const int ncq = ncols >> 2;
  const int ntasks1 = 32 * ncq;
  for (int t = tid; t < ntasks1; t += 256) {
    int ch = t / ncq, cq = t - ch * ncq;
    float4 v = *(const float4*)(src + (size_t)ch * ncols + 4 * cq);
    unsigned short* d = &lds[ch][4 * cq];
    d[0] = f2bf(v.x); d[1] = f2bf(v.y); d[2] = f2bf(v.z); d[3] = f2bf(v.w);
  }
  // zero pad cols [ncols, ntiles*16)
  const int padw2 = (ntiles * 16 - ncols) >> 1; // uints per row
  for (int t = tid; t < 32 * padw2; t += 256) {
    int r = t / padw2, c = t - r * padw2;
    *(unsigned*)&lds[r][ncols + 2 * c] = 0;
  }
  __syncthreads();

  // stage 2: fragment assembly, coalesced uint4 stores
  const int ntasks2 = ntiles * 64;
  for (int t = tid; t < ntasks2; t += 256) {
    int tile = t >> 6, l = t & 63;
    int q = l >> 4, li = l & 15;
    int col = tile * 16 + li;
    unsigned h[8];
#pragma unroll
    for (int e = 0; e < 8; ++e) h[e] = lds[q * 8 + e][col];
    uint4 u;
    u.x = h[0] | (h[1] << 16);
    u.y = h[2] | (h[3] << 16);
    u.z = h[4] | (h[5] << 16);
    u.w = h[6] | (h[7] << 16);
    dst[t] = u;
  }
}

__global__ void __launch_bounds__(256, 4) triplet_main(
    const uint4* __restrict__ ws, const float* __restrict__ coords,
    float* __restrict__ partials) {
  __shared__ uint4 bbuf[2][14][64]; // 28672 B, B frags for one 64-ch chunk
  __shared__ float red[3][4];
  const int tid = threadIdx.x;
  const int lane = tid & 63;
  const int li = lane & 15;
  const int quad = lane >> 4;
  const int w = tid >> 6;

  // block order: 16 consecutive blocks share B(j,n)
  int b = blockIdx.x;
  int jn = b >> 4, u = b & 15;
  int j = jn >> 6, n = jn & 63;
  const uint4 *abase, *bbase = ws + B_OFF + (size_t)(j * NN + n) * B_PER_MAT;
  const float *cqp, *ckp = coords + (j * NN + n) * 4;
  int Q, Wq, ntA, rowbase;
  if (u < 4) { // gl term: q = gl_sa[1-j], k = gl_pr[j]
    rowbase = u * 64;
    Q = 196; Wq = 14; ntA = 13;
    abase = ws + AGL_OFF + (size_t)((1 - j) * NN + n) * AGL_PER_MAT;
    cqp = coords + ((1 - j) * NN + n) * 4;
  } else { // lo term i
    int v = u - 4, i = v >> 1, g = v & 1;
    rowbase = g * 64;
    Q = 100; Wq = 10; ntA = 7;
    abase = ws + ALO_OFF + (size_t)(i * NN + n) * ALO_PER_MAT;
    cqp = coords + ((2 + i) * NN + n) * 4;
  }
  const int rt = (rowbase >> 4) + w; // this wave's A row-tile
  const bool active = rt < ntA;
  const uint4* ap = abase + (size_t)rt * 64 + lane;

  f32x4 acc[14];
#pragma unroll
  for (int t = 0; t < 14; ++t) acc[t] = 0.0f;

#pragma unroll 1
  for (int c8 = 0; c8 < 4; ++c8) { // 64-ch chunk = kc8 pair
    // A frags for this chunk (direct from ws, 1 KB/wave/instr)
    uint4 a0, a1;
    if (active) {
      a0 = ap[(size_t)(2 * c8) * ntA * 64];
      a1 = ap[(size_t)(2 * c8 + 1) * ntA * 64];
    }
    // stage B chunk: pure uint4 copy, lane-linear both sides
    const uint4* bs = bbase + (size_t)c8 * (2 * 14 * 64);
#pragma unroll
    for (int it = 0; it < 7; ++it) {
      int idx = it * 256 + tid;
      int kcL = idx / 896, rr = idx - kcL * 896;
      ((uint4*)bbuf)[idx] = bs[idx];
      (void)rr;
    }
    __syncthreads();
    if (active) {
#pragma unroll
      for (int t = 0; t < 14; ++t) {
        short8 bf = __builtin_bit_cast(short8, bbuf[0][t][lane]);
        acc[t] = __builtin_amdgcn_mfma_f32_16x16x32_bf16(
            __builtin_bit_cast(short8, a0), bf, acc[t], 0, 0, 0);
      }
#pragma unroll
      for (int t = 0; t < 14; ++t) {
        short8 bf = __builtin_bit_cast(short8, bbuf[1][t][lane]);
        acc[t] = __builtin_amdgcn_mfma_f32_16x16x32_bf16(
            __builtin_bit_cast(short8, a1), bf, acc[t], 0, 0, 0);
      }
    }
    __syncthreads();
  }

  // ---- geometry ----
  const float qx0 = cqp[0], qy0 = cqp[1];
  const float bwq = (cqp[2] - qx0) / (float)Wq;
  const float bhq = (cqp[3] - qy0) / (float)Wq;
  const float kx0 = ckp[0], ky0 = ckp[1];
  const float bwk = (ckp[2] - kx0) / 14.0f;
  const float bhk = (ckp[3] - ky0) / 14.0f;
  const float qd = sqrtf(bwq * bwq + bhq * bhq);
  const float kd = sqrtf(bwk * bwk + bhk * bhk);
  const float md = fmaxf(qd, kd);
  const float INFV = __builtin_inff();

  float ckx[14], cky[14];
  unsigned kvalid = 0;
#pragma unroll
  for (int t = 0; t < 14; ++t) {
    int col = t * 16 + li;
    if (col < 196) kvalid |= (1u << t);
    int xk = col % 14, yk = col / 14;
    ckx[t] = ((float)xk + 0.5f) * bwk + kx0;
    cky[t] = ((float)yk + 0.5f) * bhk + ky0;
  }

  // ---- fused epilogue on MFMA C layout: quad owns rows quad*4+reg ----
  float psum = 0.f, pcnt = 0.f, nsum = 0.f;
#pragma unroll
  for (int rg = 0; rg < 4; ++rg) {
    int r = rowbase + w * 16 + quad * 4 + rg; // quad-uniform
    if (r < Q) {
      int x = r % Wq, y = r / Wq;
      float cqx = ((float)x + 0.5f) * bwq + qx0;
      float cqy = ((float)y + 0.5f) * bhq + qy0;
      float mv[14];
#pragma unroll
      for (int t = 0; t < 14; ++t) {
        float v = -2.0f * acc[t][rg];
        float dx = cqx - ckx[t], dy = cqy - cky[t];
        float dist = sqrtf(dx * dx + dy * dy) / md;
        bool kv = (kvalid >> t) & 1;
        bool pos = kv && (dist < 0.7f);
        psum += pos ? v : 0.0f;
        pcnt += pos ? 1.0f : 0.0f;
        mv[t] = (kv && !pos) ? v : INFV;
      }
      float lmin = mv[0];
#pragma unroll
      for (int t = 1; t < 14; ++t) lmin = fminf(lmin, mv[t]);
      float total = 0.f, first = 0.f;
#pragma unroll 1
      for (int s = 0; s < 10; ++s) {
        float m = rowMin16(lmin);
        if (s == 0) first = m;
        total += m;
        unsigned long long bal = __ballot(lmin == m);
        unsigned qb = (unsigned)((bal >> (quad * 16)) & 0xFFFFull);
        int leader = __ffs(qb) - 1;
        if (li == leader) { // one lane per quad: kill first match, refresh min
          bool done = false;
#pragma unroll
          for (int t = 0; t < 14; ++t) {
            bool hit = !done && (mv[t] == m);
            mv[t] = hit ? INFV : mv[t];
            done = done || hit;
          }
          lmin = mv[0];
#pragma unroll
          for (int t = 1; t < 14; ++t) lmin = fminf(lmin, mv[t]);
        }
      }
      if (li == 0) nsum += (total - first) * (1.0f / 9.0f);
    }
  }

  psum = waveSum(psum);
  pcnt = waveSum(pcnt);
  nsum = waveSum(nsum);
  if (lane == 0) {
    red[0][w] = psum;
    red[1][w] = pcnt;
    red[2][w] = nsum;
  }
  __syncthreads();
  if (tid == 0) {
    float* pb = partials + (size_t)blockIdx.x * 3;
    pb[0] = red[0][0] + red[0][1] + red[0][2] + red[0][3];
    pb[1] = red[1][0] + red[1][1] + red[1][2] + red[1][3];
    pb[2] = red[2][0] + red[2][1] + red[2][2] + red[2][3];
  }
}

__global__ void __launch_bounds__(256) finalize_kernel(
    const float* __restrict__ partials, float* __restrict__ out) {
  int tid = threadIdx.x;
  float sum = 0.f;
  for (int e = tid; e < 14 * NN; e += 256) {
    float P = 0.f, C = 0.f, Ns = 0.f, Qf;
    if (e < 128) { // gl term t: blocks ((t*64+n)*16 + 0..3)
      int t = e >> 6, n = e & 63;
      Qf = 196.0f;
      int base = ((t * 64 + n) * 16) * 3;
#pragma unroll
      for (int g = 0; g < 4; ++g) {
        P += partials[base + 3 * g];
        C += partials[base + 3 * g + 1];
        Ns += partials[base + 3 * g + 2];
      }
    } else { // lo term (j,i): blocks ((j*64+n)*16 + 4 + 2i + {0,1})
      int s = e - 128;
      int idx = s >> 6, n = s & 63;
      int j = idx / 6, i = idx - 6 * j;
      Qf = 100.0f;
      int base = ((j * 64 + n) * 16 + 4 + 2 * i) * 3;
#pragma unroll
      for (int g = 0; g < 2; ++g) {
        P += partials[base + 3 * g];
        C += partials[base + 3 * g + 1];
        Ns += partials[base + 3 * g + 2];
      }
    }
    float positives = P / (C + 1e-6f);
    float negatives = Ns / Qf;
    sum += fmaxf(0.0f, 100.0f - (negatives - 2.0f * positives));
  }
  sum = waveSum(sum);
  __shared__ float ssum[4];
  if ((tid & 63) == 0) ssum[tid >> 6] = sum;
  __syncthreads();
  if (tid == 0) out[0] = (ssum[0] + ssum[1] + ssum[2] + ssum[3]) * (1.0f / (14 * NN));
}

extern "C" void kernel_launch(void* const* d_in, const int* in_sizes, int n_in,
                              void* d_out, int out_size, void* d_ws, size_t ws_size,
                              hipStream_t stream) {
  const float* gl_sa = (const float*)d_in[0];
  const float* lo_sa = (const float*)d_in[1];
  const float* gl_pr = (const float*)d_in[2];
  const float* coords = (const float*)d_in[3];
  uint4* frags = (uint4*)d_ws;
  float* partials = (float*)d_ws + PART_OFF_F;
  float* out = (float*)d_out;

  convert_kernel<<<5120, 256, 0, stream>>>(gl_sa, lo_sa, gl_pr, frags);
  triplet_main<<<2048, 256, 0, stream>>>(frags, coords, partials);
  finalize_kernel<<<1, 256, 0, stream>>>(partials, out);
}

// Round 6
// 171.956 us; speedup vs baseline: 1.3325x; 1.2208x over previous
//
#include <hip/hip_runtime.h>

#define NN 64
// ---- ws layout (uint4 units) ----
#define B_PER_MAT (8 * 14 * 64) // 7168
#define B_OFF 0
#define AGL_PER_MAT (8 * 13 * 64) // 6656
#define AGL_OFF (128 * B_PER_MAT) // 917504
#define ALO_PER_MAT (8 * 7 * 64) // 3584
#define ALO_OFF (AGL_OFF + 128 * AGL_PER_MAT) // 1769472
#define PART_OFF_F ((ALO_OFF + 384 * ALO_PER_MAT) * 4) // float offset 12582912

typedef __attribute__((ext_vector_type(8))) short short8;
typedef __attribute__((ext_vector_type(4))) float f32x4;

__device__ __forceinline__ float waveSum(float v) {
#pragma unroll
  for (int m = 1; m < 64; m <<= 1) v += __shfl_xor(v, m, 64);
  return v;
}

// min across each 16-lane DPP row via quad_perm/row_ror (VALU, no LDS)
__device__ __forceinline__ float rowMin16(float v) {
  int x = __builtin_bit_cast(int, v);
  v = fminf(v, __builtin_bit_cast(float, __builtin_amdgcn_update_dpp(x, x, 0xB1, 0xF, 0xF, true)));
  x = __builtin_bit_cast(int, v);
  v = fminf(v, __builtin_bit_cast(float, __builtin_amdgcn_update_dpp(x, x, 0x4E, 0xF, 0xF, true)));
  x = __builtin_bit_cast(int, v);
  v = fminf(v, __builtin_bit_cast(float, __builtin_amdgcn_update_dpp(x, x, 0x124, 0xF, 0xF, true)));
  x = __builtin_bit_cast(int, v);
  v = fminf(v, __builtin_bit_cast(float, __builtin_amdgcn_update_dpp(x, x, 0x128, 0xF, 0xF, true)));
  return v;
}

// RNE float -> bf16
__device__ __forceinline__ unsigned short f2bf(float f) {
  unsigned u = __builtin_bit_cast(unsigned, f);
  u += 0x7FFFu + ((u >> 16) & 1u);
  return (unsigned short)(u >> 16);
}
__device__ __forceinline__ unsigned packbf(float a, float b) {
  return (unsigned)f2bf(a) | ((unsigned)f2bf(b) << 16);
}

// Register-transpose convert: one block per (matrix, kc8).
// frag layout per mat: [kc8(8)][tile][lane=quad*16+li][8 bf16]
// element e of frag = src[(kc8*32 + quad*8 + e)*ncols + tile*16 + li]
// task = (quad = tid>>6, colq = tid&63): 8 coalesced float4 loads -> pack ->
// 4 contiguous uint4 stores. No LDS.
__global__ void __launch_bounds__(256) convert_kernel(
    const float* __restrict__ gl_sa, const float* __restrict__ lo_sa,
    const float* __restrict__ gl_pr, uint4* __restrict__ ws) {
  const int b = blockIdx.x;
  const int m = b >> 3, kc8 = b & 7;
  const float* src;
  uint4* dst;
  int ncols, ntiles;
  if (m < 128) {
    src = gl_pr + (size_t)m * 256 * 196;
    dst = ws + B_OFF + (size_t)m * B_PER_MAT + kc8 * 14 * 64;
    ncols = 196; ntiles = 14;
  } else if (m < 256) {
    int mm = m - 128;
    src = gl_sa + (size_t)mm * 256 * 196;
    dst = ws + AGL_OFF + (size_t)mm * AGL_PER_MAT + kc8 * 13 * 64;
    ncols = 196; ntiles = 13;
  } else {
    int mm = m - 256;
    src = lo_sa + (size_t)mm * 256 * 100;
    dst = ws + ALO_OFF + (size_t)mm * ALO_PER_MAT + kc8 * 7 * 64;
    ncols = 100; ntiles = 7;
  }
  src += (size_t)kc8 * 32 * ncols;

  const int quad = threadIdx.x >> 6, colq = threadIdx.x & 63;
  if (colq >= ntiles * 4) return;
  const int col0 = colq * 4;
  uint4 u0, u1, u2, u3;
  if (col0 < ncols) {
    const float* p = src + (size_t)(quad * 8) * ncols + col0;
    float4 g[8];
#pragma unroll
    for (int e = 0; e < 8; ++e) g[e] = *(const float4*)(p + (size_t)e * ncols);
    u0.x = packbf(g[0].x, g[1].x); u0.y = packbf(g[2].x, g[3].x);
    u0.z = packbf(g[4].x, g[5].x); u0.w = packbf(g[6].x, g[7].x);
    u1.x = packbf(g[0].y, g[1].y); u1.y = packbf(g[2].y, g[3].y);
    u1.z = packbf(g[4].y, g[5].y); u1.w = packbf(g[6].y, g[7].y);
    u2.x = packbf(g[0].z, g[1].z); u2.y = packbf(g[2].z, g[3].z);
    u2.z = packbf(g[4].z, g[5].z); u2.w = packbf(g[6].z, g[7].z);
    u3.x = packbf(g[0].w, g[1].w); u3.y = packbf(g[2].w, g[3].w);
    u3.z = packbf(g[4].w, g[5].w); u3.w = packbf(g[6].w, g[7].w);
  } else {
    u0 = u1 = u2 = u3 = make_uint4(0, 0, 0, 0);
  }
  const int tile = colq >> 2, li0 = col0 & 15;
  uint4* d = dst + (size_t)tile * 64 + quad * 16 + li0;
  d[0] = u0; d[1] = u1; d[2] = u2; d[3] = u3;
}

__global__ void __launch_bounds__(256, 4) triplet_main(
    const uint4* __restrict__ ws, const float* __restrict__ coords,
    float* __restrict__ partials) {
  __shared__ uint4 bbuf[2][14][64]; // 28672 B, B frags for one 64-ch chunk
  __shared__ float red[3][4];
  const int tid = threadIdx.x;
  const int lane = tid & 63;
  const int li = lane & 15;
  const int quad = lane >> 4;
  const int w = tid >> 6;

  // block order: 16 consecutive blocks share B(j,n)
  int b = blockIdx.x;
  int jn = b >> 4, u = b & 15;
  int j = jn >> 6, n = jn & 63;
  const uint4 *abase, *bbase = ws + B_OFF + (size_t)(j * NN + n) * B_PER_MAT;
  const float *cqp, *ckp = coords + (j * NN + n) * 4;
  int Q, Wq, ntA, rowbase;
  if (u < 4) { // gl term: q = gl_sa[1-j], k = gl_pr[j]
    rowbase = u * 64;
    Q = 196; Wq = 14; ntA = 13;
    abase = ws + AGL_OFF + (size_t)((1 - j) * NN + n) * AGL_PER_MAT;
    cqp = coords + ((1 - j) * NN + n) * 4;
  } else { // lo term i
    int v = u - 4, i = v >> 1, g = v & 1;
    rowbase = g * 64;
    Q = 100; Wq = 10; ntA = 7;
    abase = ws + ALO_OFF + (size_t)(i * NN + n) * ALO_PER_MAT;
    cqp = coords + ((2 + i) * NN + n) * 4;
  }
  const int rt = (rowbase >> 4) + w; // this wave's A row-tile
  const bool active = rt < ntA;
  const uint4* ap = abase + (size_t)rt * 64 + lane;

  f32x4 acc[14];
#pragma unroll
  for (int t = 0; t < 14; ++t) acc[t] = 0.0f;

#pragma unroll 1
  for (int c8 = 0; c8 < 4; ++c8) { // 64-ch chunk = kc8 pair
    // A frags for this chunk (direct from ws, 1 KB/wave/instr)
    uint4 a0, a1;
    if (active) {
      a0 = ap[(size_t)(2 * c8) * ntA * 64];
      a1 = ap[(size_t)(2 * c8 + 1) * ntA * 64];
    }
    // stage B chunk: async global->LDS, wave-uniform base + lane*16
    const uint4* bs = bbase + (size_t)c8 * (2 * 14 * 64);
#pragma unroll
    for (int it = 0; it < 7; ++it) {
      int idx = it * 256 + (w << 6); // wave-uniform
      __builtin_amdgcn_global_load_lds(
          (const __attribute__((address_space(1))) void*)(bs + idx + lane),
          (__attribute__((address_space(3))) void*)((uint4*)bbuf + idx),
          16, 0, 0);
    }
    __syncthreads();
    if (active) {
#pragma unroll
      for (int t = 0; t < 14; ++t) {
        short8 bf = __builtin_bit_cast(short8, bbuf[0][t][lane]);
        acc[t] = __builtin_amdgcn_mfma_f32_16x16x32_bf16(
            __builtin_bit_cast(short8, a0), bf, acc[t], 0, 0, 0);
      }
#pragma unroll
      for (int t = 0; t < 14; ++t) {
        short8 bf = __builtin_bit_cast(short8, bbuf[1][t][lane]);
        acc[t] = __builtin_amdgcn_mfma_f32_16x16x32_bf16(
            __builtin_bit_cast(short8, a1), bf, acc[t], 0, 0, 0);
      }
    }
    __syncthreads();
  }

  // ---- geometry ----
  const float qx0 = cqp[0], qy0 = cqp[1];
  const float bwq = (cqp[2] - qx0) / (float)Wq;
  const float bhq = (cqp[3] - qy0) / (float)Wq;
  const float kx0 = ckp[0], ky0 = ckp[1];
  const float bwk = (ckp[2] - kx0) / 14.0f;
  const float bhk = (ckp[3] - ky0) / 14.0f;
  const float qd = sqrtf(bwq * bwq + bhq * bhq);
  const float kd = sqrtf(bwk * bwk + bhk * bhk);
  const float md = fmaxf(qd, kd);
  const float thr2 = 0.49f * md * md; // dist<0.7 <=> d2 < (0.7*md)^2
  const float INFV = __builtin_inff();

  float ckx[14], cky[14];
  unsigned kvalid = 0;
#pragma unroll
  for (int t = 0; t < 14; ++t) {
    int col = t * 16 + li;
    if (col < 196) kvalid |= (1u << t);
    int xk = col % 14, yk = col / 14; // compile-time 14: magic mul
    ckx[t] = ((float)xk + 0.5f) * bwk + kx0;
    cky[t] = ((float)yk + 0.5f) * bhk + ky0;
  }

  // r/Wq via magic multiply (r < 256): 4682 for 14, 6554 for 10
  const unsigned Mdiv = (Wq == 14) ? 4682u : 6554u;
  unsigned r0u = (unsigned)(rowbase + w * 16 + quad * 4);
  unsigned yq = (r0u * Mdiv) >> 16;
  unsigned xq = r0u - yq * (unsigned)Wq;

  // ---- fused epilogue on MFMA C layout: quad owns rows quad*4+rg ----
  float psum = 0.f, pcnt = 0.f, nsum = 0.f;
#pragma unroll
  for (int rg = 0; rg < 4; ++rg) {
    int r = rowbase + w * 16 + quad * 4 + rg; // quad-uniform
    if (r < Q) {
      float cqx = ((float)xq + 0.5f) * bwq + qx0;
      float cqy = ((float)yq + 0.5f) * bhq + qy0;
      // per-lane sorted smallest-5 + min-of-rest, via insertion
      float s0v = INFV, s1v = INFV, s2v = INFV, s3v = INFV, s4v = INFV,
            rest = INFV;
#pragma unroll
      for (int t = 0; t < 14; ++t) {
        float v = -2.0f * acc[t][rg];
        float dx = cqx - ckx[t], dy = cqy - cky[t];
        float d2 = dx * dx + dy * dy;
        bool kv = (kvalid >> t) & 1;
        bool pos = kv && (d2 < thr2);
        psum += pos ? v : 0.0f;
        pcnt += pos ? 1.0f : 0.0f;
        float a = (kv && !pos) ? v : INFV;
        float mn;
        mn = fminf(a, s0v); a = fmaxf(a, s0v); s0v = mn;
        mn = fminf(a, s1v); a = fmaxf(a, s1v); s1v = mn;
        mn = fminf(a, s2v); a = fmaxf(a, s2v); s2v = mn;
        mn = fminf(a, s3v); a = fmaxf(a, s3v); s3v = mn;
        mn = fminf(a, s4v); a = fmaxf(a, s4v); s4v = mn;
        rest = fminf(rest, a);
      }
      float mm = rowMin16(s0v);
      float first = mm, total = mm;
      {
        unsigned long long bal = __ballot(s0v == mm);
        unsigned qb = (unsigned)(bal >> (quad << 4)) & 0xFFFFu;
        if (li == __ffs(qb) - 1) {
          s0v = s1v; s1v = s2v; s2v = s3v; s3v = s4v; s4v = rest; rest = INFV;
        }
      }
#pragma unroll 1
      for (int s = 1; s < 10; ++s) {
        mm = rowMin16(s0v);
        total += mm;
        unsigned long long bal = __ballot(s0v == mm);
        unsigned qb = (unsigned)(bal >> (quad << 4)) & 0xFFFFu;
        if (li == __ffs(qb) - 1) {
          s0v = s1v; s1v = s2v; s2v = s3v; s3v = s4v; s4v = rest; rest = INFV;
        }
      }
      if (li == 0) nsum += (total - first) * (1.0f / 9.0f);
    }
    xq++;
    if (xq == (unsigned)Wq) { xq = 0; yq++; }
  }

  psum = waveSum(psum);
  pcnt = waveSum(pcnt);
  nsum = waveSum(nsum);
  if (lane == 0) {
    red[0][w] = psum;
    red[1][w] = pcnt;
    red[2][w] = nsum;
  }
  __syncthreads();
  if (tid == 0) {
    float* pb = partials + (size_t)blockIdx.x * 3;
    pb[0] = red[0][0] + red[0][1] + red[0][2] + red[0][3];
    pb[1] = red[1][0] + red[1][1] + red[1][2] + red[1][3];
    pb[2] = red[2][0] + red[2][1] + red[2][2] + red[2][3];
  }
}

__global__ void __launch_bounds__(256) finalize_kernel(
    const float* __restrict__ partials, float* __restrict__ out) {
  int tid = threadIdx.x;
  float sum = 0.f;
  for (int e = tid; e < 14 * NN; e += 256) {
    float P = 0.f, C = 0.f, Ns = 0.f, Qf;
    if (e < 128) { // gl term t: blocks ((t*64+n)*16 + 0..3)
      int t = e >> 6, n = e & 63;
      Qf = 196.0f;
      int base = ((t * 64 + n) * 16) * 3;
#pragma unroll
      for (int g = 0; g < 4; ++g) {
        P += partials[base + 3 * g];
        C += partials[base + 3 * g + 1];
        Ns += partials[base + 3 * g + 2];
      }
    } else { // lo term (j,i): blocks ((j*64+n)*16 + 4 + 2i + {0,1})
      int s = e - 128;
      int idx = s >> 6, n = s & 63;
      int j = idx / 6, i = idx - 6 * j;
      Qf = 100.0f;
      int base = ((j * 64 + n) * 16 + 4 + 2 * i) * 3;
#pragma unroll
      for (int g = 0; g < 2; ++g) {
        P += partials[base + 3 * g];
        C += partials[base + 3 * g + 1];
        Ns += partials[base + 3 * g + 2];
      }
    }
    float positives = P / (C + 1e-6f);
    float negatives = Ns / Qf;
    sum += fmaxf(0.0f, 100.0f - (negatives - 2.0f * positives));
  }
  sum = waveSum(sum);
  __shared__ float ssum[4];
  if ((tid & 63) == 0) ssum[tid >> 6] = sum;
  __syncthreads();
  if (tid == 0) out[0] = (ssum[0] + ssum[1] + ssum[2] + ssum[3]) * (1.0f / (14 * NN));
}

extern "C" void kernel_launch(void* const* d_in, const int* in_sizes, int n_in,
                              void* d_out, int out_size, void* d_ws, size_t ws_size,
                              hipStream_t stream) {
  const float* gl_sa = (const float*)d_in[0];
  const float* lo_sa = (const float*)d_in[1];
  const float* gl_pr = (const float*)d_in[2];
  const float* coords = (const float*)d_in[3];
  uint4* frags = (uint4*)d_ws;
  float* partials = (float*)d_ws + PART_OFF_F;
  float* out = (float*)d_out;

  convert_kernel<<<5120, 256, 0, stream>>>(gl_sa, lo_sa, gl_pr, frags);
  triplet_main<<<2048, 256, 0, stream>>>(frags, coords, partials);
  finalize_kernel<<<1, 256, 0, stream>>>(partials, out);
}

// Round 7
// 167.131 us; speedup vs baseline: 1.3710x; 1.0289x over previous
//
#include <hip/hip_runtime.h>

#define NN 64
// ---- ws layout (uint4 units) ----
#define B_PER_MAT (8 * 14 * 64) // 7168
#define B_OFF 0
#define PART_OFF_F (128 * B_PER_MAT * 4) // float offset (after 14.7 MB B frags)

typedef __attribute__((ext_vector_type(8))) short short8;
typedef __attribute__((ext_vector_type(4))) float f32x4;

__device__ __forceinline__ float waveSum(float v) {
#pragma unroll
  for (int m = 1; m < 64; m <<= 1) v += __shfl_xor(v, m, 64);
  return v;
}

// min across each 16-lane DPP row via quad_perm/row_ror (VALU, no LDS)
__device__ __forceinline__ float rowMin16(float v) {
  int x = __builtin_bit_cast(int, v);
  v = fminf(v, __builtin_bit_cast(float, __builtin_amdgcn_update_dpp(x, x, 0xB1, 0xF, 0xF, true)));
  x = __builtin_bit_cast(int, v);
  v = fminf(v, __builtin_bit_cast(float, __builtin_amdgcn_update_dpp(x, x, 0x4E, 0xF, 0xF, true)));
  x = __builtin_bit_cast(int, v);
  v = fminf(v, __builtin_bit_cast(float, __builtin_amdgcn_update_dpp(x, x, 0x124, 0xF, 0xF, true)));
  x = __builtin_bit_cast(int, v);
  v = fminf(v, __builtin_bit_cast(float, __builtin_amdgcn_update_dpp(x, x, 0x128, 0xF, 0xF, true)));
  return v;
}

// RNE float -> bf16
__device__ __forceinline__ unsigned short f2bf(float f) {
  unsigned u = __builtin_bit_cast(unsigned, f);
  u += 0x7FFFu + ((u >> 16) & 1u);
  return (unsigned short)(u >> 16);
}
__device__ __forceinline__ unsigned packbf(float a, float b) {
  return (unsigned)f2bf(a) | ((unsigned)f2bf(b) << 16);
}

// Register-transpose convert of gl_pr only: one block per (matrix, kc8).
// frag layout per mat: [kc8(8)][tile(14)][lane=quad*16+li][8 bf16]
// element e of frag = src[(kc8*32 + quad*8 + e)*196 + tile*16 + li]
__global__ void __launch_bounds__(256) convert_b_kernel(
    const float* __restrict__ gl_pr, uint4* __restrict__ ws) {
  const int b = blockIdx.x;
  const int m = b >> 3, kc8 = b & 7;
  const float* src = gl_pr + (size_t)m * 256 * 196 + (size_t)kc8 * 32 * 196;
  uint4* dst = ws + B_OFF + (size_t)m * B_PER_MAT + kc8 * 14 * 64;

  const int quad = threadIdx.x >> 6, colq = threadIdx.x & 63;
  if (colq >= 56) return;
  const int col0 = colq * 4;
  uint4 u0, u1, u2, u3;
  if (col0 < 196) {
    const float* p = src + (size_t)(quad * 8) * 196 + col0;
    float4 g[8];
#pragma unroll
    for (int e = 0; e < 8; ++e) g[e] = *(const float4*)(p + (size_t)e * 196);
    u0.x = packbf(g[0].x, g[1].x); u0.y = packbf(g[2].x, g[3].x);
    u0.z = packbf(g[4].x, g[5].x); u0.w = packbf(g[6].x, g[7].x);
    u1.x = packbf(g[0].y, g[1].y); u1.y = packbf(g[2].y, g[3].y);
    u1.z = packbf(g[4].y, g[5].y); u1.w = packbf(g[6].y, g[7].y);
    u2.x = packbf(g[0].z, g[1].z); u2.y = packbf(g[2].z, g[3].z);
    u2.z = packbf(g[4].z, g[5].z); u2.w = packbf(g[6].z, g[7].z);
    u3.x = packbf(g[0].w, g[1].w); u3.y = packbf(g[2].w, g[3].w);
    u3.z = packbf(g[4].w, g[5].w); u3.w = packbf(g[6].w, g[7].w);
  } else {
    u0 = u1 = u2 = u3 = make_uint4(0, 0, 0, 0);
  }
  const int tile = colq >> 2, li0 = col0 & 15;
  uint4* d = dst + (size_t)tile * 64 + quad * 16 + li0;
  d[0] = u0; d[1] = u1; d[2] = u2; d[3] = u3;
}

__global__ void __launch_bounds__(256, 4) triplet_main(
    const float* __restrict__ gl_sa, const float* __restrict__ lo_sa,
    const uint4* __restrict__ ws, const float* __restrict__ coords,
    float* __restrict__ partials) {
  __shared__ uint4 bbuf[2][14][64]; // 28672 B, B frags for one 64-ch chunk
  __shared__ float red[3][4];
  const int tid = threadIdx.x;
  const int lane = tid & 63;
  const int li = lane & 15;
  const int quad = lane >> 4;
  const int w = tid >> 6;

  // block order: 16 consecutive blocks share B(j,n)
  int b = blockIdx.x;
  int jn = b >> 4, u = b & 15;
  int j = jn >> 6, n = jn & 63;
  const uint4* bbase = ws + B_OFF + (size_t)(j * NN + n) * B_PER_MAT;
  const float *cqp, *ckp = coords + (j * NN + n) * 4;
  const float* asrc;
  int Q, Wq, ntA, rowbase;
  if (u < 4) { // gl term: q = gl_sa[1-j], k = gl_pr[j]
    rowbase = u * 64;
    Q = 196; Wq = 14; ntA = 13;
    asrc = gl_sa + (size_t)((1 - j) * NN + n) * 256 * 196;
    cqp = coords + ((1 - j) * NN + n) * 4;
  } else { // lo term i
    int v = u - 4, i = v >> 1, g = v & 1;
    rowbase = g * 64;
    Q = 100; Wq = 10; ntA = 7;
    asrc = lo_sa + (size_t)(i * NN + n) * 256 * 100;
    cqp = coords + ((2 + i) * NN + n) * 4;
  }
  const int rt = (rowbase >> 4) + w; // this wave's A row-tile
  const bool active = rt < ntA;
  const int arow = rt * 16 + li;
  const bool rvalid = active && (arow < Q);
  // lane's A gather base: channel quad*8, row arow
  const float* agp = asrc + (size_t)(quad * 8) * Q + (rvalid ? arow : 0);

  f32x4 acc[14];
#pragma unroll
  for (int t = 0; t < 14; ++t) acc[t] = 0.0f;

#pragma unroll 1
  for (int c8 = 0; c8 < 4; ++c8) { // 64-ch chunk = kc8 pair
    // A frags for this chunk: in-register gather + bf16 pack
    uint4 a0, a1;
    if (active) {
      const float* p0 = agp + (size_t)(c8 * 64) * Q;
      const float* p1 = p0 + (size_t)32 * Q;
      float v0[8], v1[8];
#pragma unroll
      for (int e = 0; e < 8; ++e) {
        v0[e] = rvalid ? p0[(size_t)e * Q] : 0.0f;
        v1[e] = rvalid ? p1[(size_t)e * Q] : 0.0f;
      }
      a0.x = packbf(v0[0], v0[1]); a0.y = packbf(v0[2], v0[3]);
      a0.z = packbf(v0[4], v0[5]); a0.w = packbf(v0[6], v0[7]);
      a1.x = packbf(v1[0], v1[1]); a1.y = packbf(v1[2], v1[3]);
      a1.z = packbf(v1[4], v1[5]); a1.w = packbf(v1[6], v1[7]);
    }
    // stage B chunk: async global->LDS, wave-uniform base + lane*16
    const uint4* bs = bbase + (size_t)c8 * (2 * 14 * 64);
#pragma unroll
    for (int it = 0; it < 7; ++it) {
      int idx = it * 256 + (w << 6); // wave-uniform
      __builtin_amdgcn_global_load_lds(
          (const __attribute__((address_space(1))) void*)(bs + idx + lane),
          (__attribute__((address_space(3))) void*)((uint4*)bbuf + idx),
          16, 0, 0);
    }
    __syncthreads();
    if (active) {
#pragma unroll
      for (int t = 0; t < 14; ++t) {
        short8 bf = __builtin_bit_cast(short8, bbuf[0][t][lane]);
        acc[t] = __builtin_amdgcn_mfma_f32_16x16x32_bf16(
            __builtin_bit_cast(short8, a0), bf, acc[t], 0, 0, 0);
      }
#pragma unroll
      for (int t = 0; t < 14; ++t) {
        short8 bf = __builtin_bit_cast(short8, bbuf[1][t][lane]);
        acc[t] = __builtin_amdgcn_mfma_f32_16x16x32_bf16(
            __builtin_bit_cast(short8, a1), bf, acc[t], 0, 0, 0);
      }
    }
    __syncthreads();
  }

  // ---- geometry ----
  const float qx0 = cqp[0], qy0 = cqp[1];
  const float bwq = (cqp[2] - qx0) / (float)Wq;
  const float bhq = (cqp[3] - qy0) / (float)Wq;
  const float kx0 = ckp[0], ky0 = ckp[1];
  const float bwk = (ckp[2] - kx0) / 14.0f;
  const float bhk = (ckp[3] - ky0) / 14.0f;
  const float qd = sqrtf(bwq * bwq + bhq * bhq);
  const float kd = sqrtf(bwk * bwk + bhk * bhk);
  const float md = fmaxf(qd, kd);
  const float thr2 = 0.49f * md * md; // dist<0.7 <=> d2 < (0.7*md)^2
  const float INFV = __builtin_inff();

  float ckx[14], cky[14];
  unsigned kvalid = 0;
#pragma unroll
  for (int t = 0; t < 14; ++t) {
    int col = t * 16 + li;
    if (col < 196) kvalid |= (1u << t);
    int xk = col % 14, yk = col / 14; // compile-time 14: magic mul
    ckx[t] = ((float)xk + 0.5f) * bwk + kx0;
    cky[t] = ((float)yk + 0.5f) * bhk + ky0;
  }

  // r/Wq via magic multiply (r < 256): 4682 for 14, 6554 for 10
  const unsigned Mdiv = (Wq == 14) ? 4682u : 6554u;
  unsigned r0u = (unsigned)(rowbase + w * 16 + quad * 4);
  unsigned yq = (r0u * Mdiv) >> 16;
  unsigned xq = r0u - yq * (unsigned)Wq;

  // ---- fused epilogue on MFMA C layout: quad owns rows quad*4+rg ----
  float psum = 0.f, pcnt = 0.f, nsum = 0.f;
#pragma unroll
  for (int rg = 0; rg < 4; ++rg) {
    int r = rowbase + w * 16 + quad * 4 + rg; // quad-uniform
    if (r < Q) {
      float cqx = ((float)xq + 0.5f) * bwq + qx0;
      float cqy = ((float)yq + 0.5f) * bhq + qy0;
      // per-lane sorted smallest-5 + min-of-rest, via insertion
      float s0v = INFV, s1v = INFV, s2v = INFV, s3v = INFV, s4v = INFV,
            rest = INFV;
#pragma unroll
      for (int t = 0; t < 14; ++t) {
        float v = -2.0f * acc[t][rg];
        float dx = cqx - ckx[t], dy = cqy - cky[t];
        float d2 = dx * dx + dy * dy;
        bool kv = (kvalid >> t) & 1;
        bool pos = kv && (d2 < thr2);
        psum += pos ? v : 0.0f;
        pcnt += pos ? 1.0f : 0.0f;
        float a = (kv && !pos) ? v : INFV;
        float mn;
        mn = fminf(a, s0v); a = fmaxf(a, s0v); s0v = mn;
        mn = fminf(a, s1v); a = fmaxf(a, s1v); s1v = mn;
        mn = fminf(a, s2v); a = fmaxf(a, s2v); s2v = mn;
        mn = fminf(a, s3v); a = fmaxf(a, s3v); s3v = mn;
        mn = fminf(a, s4v); a = fmaxf(a, s4v); s4v = mn;
        rest = fminf(rest, a);
      }
      float mm = rowMin16(s0v);
      float first = mm, total = mm;
      {
        unsigned long long bal = __ballot(s0v == mm);
        unsigned qb = (unsigned)(bal >> (quad << 4)) & 0xFFFFu;
        if (li == __ffs(qb) - 1) {
          s0v = s1v; s1v = s2v; s2v = s3v; s3v = s4v; s4v = rest; rest = INFV;
        }
      }
#pragma unroll 1
      for (int s = 1; s < 10; ++s) {
        mm = rowMin16(s0v);
        total += mm;
        unsigned long long bal = __ballot(s0v == mm);
        unsigned qb = (unsigned)(bal >> (quad << 4)) & 0xFFFFu;
        if (li == __ffs(qb) - 1) {
          s0v = s1v; s1v = s2v; s2v = s3v; s3v = s4v; s4v = rest; rest = INFV;
        }
      }
      if (li == 0) nsum += (total - first) * (1.0f / 9.0f);
    }
    xq++;
    if (xq == (unsigned)Wq) { xq = 0; yq++; }
  }

  psum = waveSum(psum);
  pcnt = waveSum(pcnt);
  nsum = waveSum(nsum);
  if (lane == 0) {
    red[0][w] = psum;
    red[1][w] = pcnt;
    red[2][w] = nsum;
  }
  __syncthreads();
  if (tid == 0) {
    float* pb = partials + (size_t)blockIdx.x * 3;
    pb[0] = red[0][0] + red[0][1] + red[0][2] + red[0][3];
    pb[1] = red[1][0] + red[1][1] + red[1][2] + red[1][3];
    pb[2] = red[2][0] + red[2][1] + red[2][2] + red[2][3];
  }
}

__global__ void __launch_bounds__(256) finalize_kernel(
    const float* __restrict__ partials, float* __restrict__ out) {
  int tid = threadIdx.x;
  float sum = 0.f;
  for (int e = tid; e < 14 * NN; e += 256) {
    float P = 0.f, C = 0.f, Ns = 0.f, Qf;
    if (e < 128) { // gl term t: blocks ((t*64+n)*16 + 0..3)
      int t = e >> 6, n = e & 63;
      Qf = 196.0f;
      int base = ((t * 64 + n) * 16) * 3;
#pragma unroll
      for (int g = 0; g < 4; ++g) {
        P += partials[base + 3 * g];
        C += partials[base + 3 * g + 1];
        Ns += partials[base + 3 * g + 2];
      }
    } else { // lo term (j,i): blocks ((j*64+n)*16 + 4 + 2i + {0,1})
      int s = e - 128;
      int idx = s >> 6, n = s & 63;
      int j = idx / 6, i = idx - 6 * j;
      Qf = 100.0f;
      int base = ((j * 64 + n) * 16 + 4 + 2 * i) * 3;
#pragma unroll
      for (int g = 0; g < 2; ++g) {
        P += partials[base + 3 * g];
        C += partials[base + 3 * g + 1];
        Ns += partials[base + 3 * g + 2];
      }
    }
    float positives = P / (C + 1e-6f);
    float negatives = Ns / Qf;
    sum += fmaxf(0.0f, 100.0f - (negatives - 2.0f * positives));
  }
  sum = waveSum(sum);
  __shared__ float ssum[4];
  if ((tid & 63) == 0) ssum[tid >> 6] = sum;
  __syncthreads();
  if (tid == 0) out[0] = (ssum[0] + ssum[1] + ssum[2] + ssum[3]) * (1.0f / (14 * NN));
}

extern "C" void kernel_launch(void* const* d_in, const int* in_sizes, int n_in,
                              void* d_out, int out_size, void* d_ws, size_t ws_size,
                              hipStream_t stream) {
  const float* gl_sa = (const float*)d_in[0];
  const float* lo_sa = (const float*)d_in[1];
  const float* gl_pr = (const float*)d_in[2];
  const float* coords = (const float*)d_in[3];
  uint4* frags = (uint4*)d_ws;
  float* partials = (float*)d_ws + PART_OFF_F;
  float* out = (float*)d_out;

  convert_b_kernel<<<1024, 256, 0, stream>>>(gl_pr, frags);
  triplet_main<<<2048, 256, 0, stream>>>(gl_sa, lo_sa, frags, coords, partials);
  finalize_kernel<<<1, 256, 0, stream>>>(partials, out);
}